// Round 12
// baseline (300.342 us; speedup 1.0000x reference)
//
#include <hip/hip_runtime.h>
#include <hip/hip_bf16.h>
#include <stdint.h>

#define DIM 128
#define ODIM 64
#define BM 128
#define BN 64
#define NSPLIT 48

typedef __attribute__((ext_vector_type(8))) __bf16 bf16x8;
typedef __attribute__((ext_vector_type(2))) __bf16 bf16x2;
typedef __attribute__((ext_vector_type(4))) float f32x4;

#define MFMA16(a, b, c) __builtin_amdgcn_mfma_f32_16x16x32_bf16((a), (b), (c), 0, 0, 0)

// c = log2(e) / (2*RBF_CO);  k = exp(-dist/(2*co)) = 2^(-c*dist) = 2^(-sqrt(c^2*d2))
// d2' = c^2*d2 = c^2*x2 + c^2*t2 + (-2c^2*t)·x  -> MFMA with A = -2c^2*t (pre-scaled
// in prepass), C initialized to c^2*(t2 + x2). No per-element fma/scale needed.
#define RBFD 10.077141124806595
#define LOG2E 1.4426950408889634
#define C2D ((LOG2E / (2.0 * RBFD)) * (LOG2E / (2.0 * RBFD)))

__device__ __forceinline__ void async_copy16(const void* g, void* l) {
  __builtin_amdgcn_global_load_lds((const __attribute__((address_space(1))) void*)g,
                                   (__attribute__((address_space(3))) void*)l, 16, 0, 0);
}

// round-half-up bf16 pack: lo=a, hi=b  (values finite positive; +0x8000 then take hi16)
// [harness-verified; do NOT swap for v_cvt_pk_bf16_f32 without isolated verification]
__device__ __forceinline__ uint32_t pack_bf16(float a, float b) {
  uint32_t ua = __builtin_bit_cast(uint32_t, a) + 0x8000u;
  uint32_t ub = __builtin_bit_cast(uint32_t, b) + 0x8000u;
  return __builtin_amdgcn_perm(ub, ua, 0x07060302u);  // lo16=a.hi16, hi16=b.hi16
}

// ---- Fast merged prepass (R11-verified). Also zeroes the done[] counters used by
// the fused reduction (same-stream ordering guarantees visibility to rbf_main;
// re-zeroed on every graph replay).
__global__ void prep_fast(const float* __restrict__ train, __bf16* __restrict__ Tb,
                          float* __restrict__ t2, const float* __restrict__ feat,
                          __bf16* __restrict__ Fb, float* __restrict__ x2,
                          const float* __restrict__ W, __bf16* __restrict__ Wt,
                          int* __restrict__ done,
                          int Ntrain, int Npad, int nFeat,
                          int trainRB, int rowRB, float scale, float tScale) {
  __shared__ float tile[64][65];
  const int b = (int)blockIdx.x;
  const int t = (int)threadIdx.x;

  if (b == 0 && t < 16) done[t] = 0;

  if (b < rowRB) {
    const float* src;
    __bf16* dst;
    float* sq;
    int nValid, nPad, row0;
    float padv, rowScale;
    if (b < trainRB) {
      src = train; dst = Tb; sq = t2; nValid = Ntrain; nPad = Npad; row0 = b * 32;
      padv = 1e30f; rowScale = tScale;  // -2*c^2
    } else {
      src = feat; dst = Fb; sq = x2; nValid = nFeat; nPad = nFeat; row0 = (b - trainRB) * 32;
      padv = 0.0f; rowScale = 1.0f;
    }
    const int r = t >> 3;        // row within block (0..31)
    const int sub = t & 7;       // 8 threads per row, 16 floats each
    const int row = row0 + r;
    if (row >= nPad) return;
    const bool valid = row < nValid;
    const float4* s4 = (const float4*)(src + (size_t)row * DIM) + sub * 4;
    float ss = 0.0f;
    __bf16 ob[16];
    #pragma unroll
    for (int q = 0; q < 4; ++q) {
      float4 u = valid ? s4[q] : make_float4(0.0f, 0.0f, 0.0f, 0.0f);
      ss += u.x * u.x + u.y * u.y + u.z * u.z + u.w * u.w;  // raw values
      ob[q * 4 + 0] = (__bf16)(u.x * rowScale);
      ob[q * 4 + 1] = (__bf16)(u.y * rowScale);
      ob[q * 4 + 2] = (__bf16)(u.z * rowScale);
      ob[q * 4 + 3] = (__bf16)(u.w * rowScale);
    }
    __bf16* d = dst + (size_t)row * DIM + sub * 16;
    *(bf16x8*)d = *(bf16x8*)&ob[0];
    *(bf16x8*)(d + 8) = *(bf16x8*)&ob[8];
    ss += __shfl_xor(ss, 1);
    ss += __shfl_xor(ss, 2);
    ss += __shfl_xor(ss, 4);
    if (sub == 0) sq[row] = valid ? ss * scale : padv;
    return;
  }

  // weights transpose (verified body, unchanged)
  int j0 = (b - rowRB) * 64;
  int jr = t >> 2;
  int cg = (t & 3) * 16;
  int j = j0 + jr;
  if (j < Ntrain) {
    const float4* src = (const float4*)(W + (size_t)j * ODIM);
    #pragma unroll
    for (int q = 0; q < 4; ++q) {
      float4 u = src[(cg >> 2) + q];
      tile[jr][cg + q * 4 + 0] = u.x;
      tile[jr][cg + q * 4 + 1] = u.y;
      tile[jr][cg + q * 4 + 2] = u.z;
      tile[jr][cg + q * 4 + 3] = u.w;
    }
  } else {
    #pragma unroll
    for (int q = 0; q < 16; ++q) tile[jr][cg + q] = 0.0f;
  }
  __syncthreads();
  int v = t >> 2;
  int jc = (t & 3) * 16;
  __bf16 ob[16];
  #pragma unroll
  for (int q = 0; q < 16; ++q) ob[q] = (__bf16)tile[jc + q][v];
  __bf16* dst = Wt + (size_t)v * Npad + j0 + jc;
  *(bf16x8*)dst = *(bf16x8*)&ob[0];
  *(bf16x8*)(dst + 8) = *(bf16x8*)&ob[8];
}

// ---- Main fused kernel (S^T formulation). Main loop = R4/R11 body VERBATIM
// (65.0 us plateau config: single-buffered sT/sW, 2 barriers/chunk, wave-private
// swizzled sP, affine fold, NSPLIT 48, (256,3), 40 KB LDS).
// NEW (ATOMIC=false): fused cross-split reduction — each block stores its partial,
// __threadfence(), atomicAdd(done[mb]); the 48th arriver reduces its mb's 48
// partials and writes final out. Last-finisher pattern: no dispatch-order or
// co-residency assumption (G16-safe, device-scope atomics). Removes the
// reduce_parts kernel + one launch gap; reduction overlaps straggler blocks.
template <bool ATOMIC>
__global__ __launch_bounds__(256, 3) void rbf_main(
    const __bf16* __restrict__ Fb, const __bf16* __restrict__ Tb,
    const __bf16* __restrict__ Wt, const float* __restrict__ t2g,
    const float* __restrict__ x2g, float* __restrict__ part,
    float* __restrict__ out, int* __restrict__ done,
    int nRows, int Npad, int nChunks) {
  __shared__ __bf16 sT[BN * DIM];   // 16 KB, XOR-swizzled 16B granules
  __shared__ __bf16 sW[ODIM * BN];  // 8 KB, XOR-swizzled 16B granules
  __shared__ __bf16 sP[BM * 64];    // 16 KB, wave-private strips; ticket aliased here post-loop

  const int tid = threadIdx.x;
  const int wave = tid >> 6;
  const int lane = tid & 63;
  const int l16 = lane & 15;
  const int g4 = lane >> 4;

  const int ns = (int)blockIdx.x;  // 0..NSPLIT-1
  const int mb = (int)blockIdx.y;  // 0..15

  // F fragments (chunk-invariant): rows mb*128 + wave*32 + nf*16 + l16, 8 k each.
  bf16x8 bF[2][4];
  #pragma unroll
  for (int nf = 0; nf < 2; ++nf)
    #pragma unroll
    for (int ko = 0; ko < 4; ++ko)
      bF[nf][ko] = *(const bf16x8*)(Fb + ((size_t)(mb * BM + wave * 32 + nf * 16 + l16)) * DIM +
                                    ko * 32 + g4 * 8);

  float x2v[2];
  #pragma unroll
  for (int nf = 0; nf < 2; ++nf)
    x2v[nf] = x2g[mb * BM + wave * 32 + nf * 16 + l16];  // pre-scaled by c^2

  f32x4 zero4 = {0.0f, 0.0f, 0.0f, 0.0f};
  f32x4 oacc[2][4];
  #pragma unroll
  for (int mo = 0; mo < 2; ++mo)
    #pragma unroll
    for (int vi = 0; vi < 4; ++vi) oacc[mo][vi] = zero4;

  for (int c = ns; c < nChunks; c += NSPLIT) {
    const int n0 = c * BN;

    // Stage T chunk [64][128] bf16. LDS granule (row,g) holds global granule g^(row&15).
    {
      const char* gT = (const char*)Tb + (size_t)n0 * 256;
      #pragma unroll
      for (int i = 0; i < 4; ++i) {
        int off = i * 4096 + wave * 1024;  // wave-uniform LDS base
        int loff = off + lane * 16;
        int row = loff >> 8;
        int gran = (loff >> 4) & 15;
        async_copy16(gT + row * 256 + ((gran ^ (row & 15)) << 4), (char*)sT + off);
      }
    }
    // Stage W chunk: sW[v][0..63] = Wt[v][n0..n0+63]; granule g holds global g^(v&7).
    {
      #pragma unroll
      for (int i = 0; i < 2; ++i) {
        int off = i * 4096 + wave * 1024;
        int loff = off + lane * 16;
        int v = loff >> 7;
        int gran = (loff >> 4) & 7;
        const char* gW = (const char*)Wt + ((size_t)v * Npad + n0) * 2 + ((gran ^ (v & 7)) << 4);
        async_copy16(gW, (char*)sW + off);
      }
    }
    // t2 for this chunk direct from global (L2-hot); drained by the same barrier.
    f32x4 t2v[4];
    #pragma unroll
    for (int mt = 0; mt < 4; ++mt)
      t2v[mt] = *(const f32x4*)(t2g + n0 + mt * 16 + g4 * 4);

    __syncthreads();

    // S^T = (-2c^2*T) · F^T + (t2' + x2') : sacc directly holds d2'.
    f32x4 sacc[4][2];
    #pragma unroll
    for (int mt = 0; mt < 4; ++mt)
      #pragma unroll
      for (int nf = 0; nf < 2; ++nf)
        #pragma unroll
        for (int r = 0; r < 4; ++r) sacc[mt][nf][r] = t2v[mt][r] + x2v[nf];

    #pragma unroll
    for (int ko = 0; ko < 4; ++ko) {
      bf16x8 a[4];
      #pragma unroll
      for (int mt = 0; mt < 4; ++mt) {
        int row = mt * 16 + l16;
        int slot = (ko * 4 + g4) ^ l16;
        a[mt] = *(const bf16x8*)((const char*)sT + row * 256 + (slot << 4));
      }
      #pragma unroll
      for (int mt = 0; mt < 4; ++mt)
        #pragma unroll
        for (int nf = 0; nf < 2; ++nf)
          sacc[mt][nf] = MFMA16(a[mt], bF[nf][ko], sacc[mt][nf]);
    }

    // elementwise: k = 2^(-sqrt(max(d2',0))) ; pack 4 bf16 -> swizzled b64 write.
    #pragma unroll
    for (int mt = 0; mt < 4; ++mt) {
      #pragma unroll
      for (int nf = 0; nf < 2; ++nf) {
        float kv[4];
        #pragma unroll
        for (int r = 0; r < 4; ++r) {
          float d2 = fmaxf(sacc[mt][nf][r], 0.0f);
          kv[r] = __builtin_amdgcn_exp2f(-__builtin_amdgcn_sqrtf(d2));
        }
        uint32_t lo = pack_bf16(kv[0], kv[1]);
        uint32_t hi = pack_bf16(kv[2], kv[3]);
        int prow = wave * 32 + nf * 16 + l16;
        int gran = (2 * mt + (g4 >> 1)) ^ (l16 & 7);
        uint2* dst = (uint2*)((char*)sP + prow * 128 + (gran << 4) + (g4 & 1) * 8);
        *dst = make_uint2(lo, hi);
      }
    }
    // NOTE: no barrier — each wave's sP strip is written and read only by itself.

    // O += P · W
    #pragma unroll
    for (int ko2 = 0; ko2 < 2; ++ko2) {
      bf16x8 p[2];
      #pragma unroll
      for (int mo = 0; mo < 2; ++mo) {
        int prow = wave * 32 + mo * 16 + l16;
        int gran = (ko2 * 4 + g4) ^ (l16 & 7);
        p[mo] = *(const bf16x8*)((const char*)sP + prow * 128 + (gran << 4));
      }
      bf16x8 w[4];
      #pragma unroll
      for (int vi = 0; vi < 4; ++vi) {
        int v = vi * 16 + l16;
        int slot = (ko2 * 4 + g4) ^ (l16 & 7);
        w[vi] = *(const bf16x8*)((const char*)sW + v * 128 + (slot << 4));
      }
      #pragma unroll
      for (int mo = 0; mo < 2; ++mo)
        #pragma unroll
        for (int vi = 0; vi < 4; ++vi)
          oacc[mo][vi] = MFMA16(p[mo], w[vi], oacc[mo][vi]);
    }
    __syncthreads();  // protect sT/sW from next chunk's staging
  }

  if (ATOMIC) {
    #pragma unroll
    for (int mo = 0; mo < 2; ++mo)
      #pragma unroll
      for (int vi = 0; vi < 4; ++vi)
        #pragma unroll
        for (int r = 0; r < 4; ++r) {
          int row = mb * BM + wave * 32 + mo * 16 + g4 * 4 + r;
          int col = vi * 16 + l16;
          atomicAdd(&out[(size_t)row * ODIM + col], oacc[mo][vi][r]);
        }
  } else {
    // Store this split's partial (same layout as before).
    float* dst = part + (size_t)ns * (size_t)nRows * ODIM;
    #pragma unroll
    for (int mo = 0; mo < 2; ++mo)
      #pragma unroll
      for (int vi = 0; vi < 4; ++vi)
        #pragma unroll
        for (int r = 0; r < 4; ++r) {
          int row = mb * BM + wave * 32 + mo * 16 + g4 * 4 + r;
          int col = vi * 16 + l16;
          dst[(size_t)row * ODIM + col] = oacc[mo][vi][r];
        }

    // Fused reduction: last block to finish this mb sums the 48 partials.
    __threadfence();  // make this block's partial stores device-visible
    int* ticketShared = (int*)sP;  // sP dead after main loop; reuse 4 bytes
    __syncthreads();  // all stores issued (threadfence orders them per-thread)
    if (tid == 0)
      *ticketShared = __hip_atomic_fetch_add(&done[mb], 1, __ATOMIC_ACQ_REL,
                                             __HIP_MEMORY_SCOPE_AGENT);
    __syncthreads();
    if (*ticketShared == NSPLIT - 1) {
      __threadfence();  // acquire side: all other splits' partials now visible
      const int base4 = mb * BM * ODIM / 4;        // f32x4 index of this mb's rows
      const int stride4 = nRows * ODIM / 4;        // f32x4 per split
      const float4* p4 = (const float4*)part;
      float4* o4 = (float4*)out;
      for (int i = tid; i < BM * ODIM / 4; i += 256) {
        float4 s = make_float4(0.0f, 0.0f, 0.0f, 0.0f);
        #pragma unroll 4
        for (int sp = 0; sp < NSPLIT; ++sp) {
          float4 v = p4[(size_t)sp * stride4 + base4 + i];
          s.x += v.x; s.y += v.y; s.z += v.z; s.w += v.w;
        }
        o4[base4 + i] = s;
      }
    }
  }
}

extern "C" void kernel_launch(void* const* d_in, const int* in_sizes, int n_in,
                              void* d_out, int out_size, void* d_ws, size_t ws_size,
                              hipStream_t stream) {
  (void)n_in;
  const float* features = (const float*)d_in[0];
  const float* train = (const float*)d_in[1];
  const float* weights = (const float*)d_in[2];
  float* out = (float*)d_out;

  const int n = in_sizes[0] / DIM;              // 2048
  const int N = in_sizes[1] / DIM;              // 50000
  const int Npad = ((N + 63) / 64) * 64;        // 50048
  const int nChunks = Npad / 64;                // 782

  size_t off = 0;
  auto alloc = [&](size_t bytes) {
    size_t o = off;
    off = (off + bytes + 255) & ~(size_t)255;
    return o;
  };
  size_t oT = alloc((size_t)Npad * DIM * 2);
  size_t oW = alloc((size_t)ODIM * Npad * 2);
  size_t oF = alloc((size_t)n * DIM * 2);
  size_t ot2 = alloc((size_t)Npad * 4);
  size_t ox2 = alloc((size_t)n * 4);
  size_t oDone = alloc(64);
  size_t oPart = alloc((size_t)NSPLIT * n * ODIM * 4);
  size_t needFull = off;

  char* ws = (char*)d_ws;
  __bf16* Tb = (__bf16*)(ws + oT);
  __bf16* Wt = (__bf16*)(ws + oW);
  __bf16* Fb = (__bf16*)(ws + oF);
  float* t2 = (float*)(ws + ot2);
  float* x2 = (float*)(ws + ox2);
  int* done = (int*)(ws + oDone);

  const float scale = (float)C2D;
  const float tScale = (float)(-2.0 * C2D);
  const int trainRB = Npad / 32;                 // 1564 (32 rows/block)
  const int rowRB = trainRB + n / 32;            // + 64
  const int wBlocks = Npad / 64;                 // 782
  prep_fast<<<rowRB + wBlocks, 256, 0, stream>>>(train, Tb, t2, features, Fb, x2,
                                                 weights, Wt, done, N, Npad, n,
                                                 trainRB, rowRB, scale, tScale);

  const int mBlocks = n / BM;                    // 16
  dim3 grid(NSPLIT, mBlocks);                    // 768 blocks = 3/CU

  if (ws_size >= needFull) {
    float* part = (float*)(ws + oPart);
    rbf_main<false><<<grid, 256, 0, stream>>>(Fb, Tb, Wt, t2, x2, part, out, done,
                                              n, Npad, nChunks);
  } else {
    hipMemsetAsync(d_out, 0, (size_t)out_size * sizeof(float), stream);
    rbf_main<true><<<grid, 256, 0, stream>>>(Fb, Tb, Wt, t2, x2, nullptr, out, done,
                                             n, Npad, nChunks);
  }
}